// Round 1
// baseline (577.600 us; speedup 1.0000x reference)
//
#include <hip/hip_runtime.h>
#include <math.h>

#define N_NODES 61440
#define N_EDGES 245760
#define BATCH   2048
#define ATOMS   30
#define F_LEN   64
#define DIM     256
#define NUM_NEI 32
#define MF      40
#define NPB0    16
#define NPB1    16

// ---------------- degree counts ----------------
__global__ void k_deg(const int* __restrict__ esrc, const int* __restrict__ edst,
                      int* deg_out, int* deg_in) {
    int e = blockIdx.x * 256 + threadIdx.x;
    if (e < N_EDGES) {
        atomicAdd(&deg_out[esrc[e]], 1);
        atomicAdd(&deg_in[edst[e]], 1);
    }
}

// ---------------- layer-0 scatter: agg0[dst] += onehot(src)*norm_src ----------------
__global__ void k_scatter0(const int* __restrict__ nf, const int* __restrict__ esrc,
                           const int* __restrict__ edst, const int* __restrict__ deg_out,
                           float* agg0) {
    int e = blockIdx.x * 4 + (threadIdx.x >> 6);
    int lane = threadIdx.x & 63;
    if (e >= N_EDGES) return;
    int s = esrc[e], d = edst[e];
    float ns = rsqrtf((float)max(deg_out[s], 1));
    int n0 = nf[s*4+0], n1 = nf[s*4+1], n2 = nf[s*4+2], n3 = nf[s*4+3];
    int cnt = (n0 == lane) + (n1 == lane) + (n2 == lane) + (n3 == lane);
    if (cnt) atomicAdd(&agg0[d*64 + lane], (float)cnt * ns);
}

// ---------------- gemm0: h1 = relu(norm_dst * (agg0 @ W0) + b0) ----------------
__global__ void k_gemm0(const float* __restrict__ agg0, const int* __restrict__ deg_in,
                        const float* __restrict__ W0, const float* __restrict__ b0,
                        float* h1) {
    __shared__ float la[NPB0 * 64];
    __shared__ float lnd[NPB0];
    int n0 = blockIdx.x * NPB0;
    int t = threadIdx.x;
    for (int i = t; i < NPB0 * 64; i += 256) la[i] = agg0[n0*64 + i];
    if (t < NPB0) lnd[t] = rsqrtf((float)max(deg_in[n0 + t], 1));
    __syncthreads();
    float acc[NPB0];
#pragma unroll
    for (int i = 0; i < NPB0; i++) acc[i] = 0.f;
    for (int f = 0; f < 64; f++) {
        float wf = W0[f*DIM + t];
#pragma unroll
        for (int i = 0; i < NPB0; i++) acc[i] += la[i*64 + f] * wf;
    }
    float bt = b0[t];
#pragma unroll
    for (int i = 0; i < NPB0; i++) {
        float z = acc[i] * lnd[i] + bt;
        h1[(size_t)(n0 + i)*DIM + t] = fmaxf(z, 0.f);
    }
}

// ---------------- layer-1 scatter: agg1[dst] += h1[src]*norm_src ----------------
__global__ void k_scatter1(const float* __restrict__ h1, const int* __restrict__ esrc,
                           const int* __restrict__ edst, const int* __restrict__ deg_out,
                           float* agg1) {
    int e = blockIdx.x * 4 + (threadIdx.x >> 6);
    int lane = threadIdx.x & 63;
    if (e >= N_EDGES) return;
    int s = esrc[e], d = edst[e];
    float ns = rsqrtf((float)max(deg_out[s], 1));
#pragma unroll
    for (int j = 0; j < 4; j++) {
        int tt = lane + j*64;
        float v = h1[(size_t)s*DIM + tt] * ns;
        if (v != 0.f) atomicAdd(&agg1[(size_t)d*DIM + tt], v);
    }
}

// ---------------- gemm1: h2 = norm_dst * (agg1 @ W1) + b1 ----------------
__global__ void k_gemm1(const float* __restrict__ agg1, const int* __restrict__ deg_in,
                        const float* __restrict__ W1, const float* __restrict__ b1,
                        float* h2) {
    __shared__ float la[NPB1 * DIM];
    __shared__ float lnd[NPB1];
    int n0 = blockIdx.x * NPB1;
    int t = threadIdx.x;
    for (int i = t; i < NPB1 * DIM; i += 256) la[i] = agg1[(size_t)n0*DIM + i];
    if (t < NPB1) lnd[t] = rsqrtf((float)max(deg_in[n0 + t], 1));
    __syncthreads();
    float acc[NPB1];
#pragma unroll
    for (int i = 0; i < NPB1; i++) acc[i] = 0.f;
    for (int f = 0; f < DIM; f++) {
        float wf = W1[f*DIM + t];
#pragma unroll
        for (int i = 0; i < NPB1; i++) acc[i] += la[i*DIM + f] * wf;
    }
    float bt = b1[t];
#pragma unroll
    for (int i = 0; i < NPB1; i++) {
        h2[(size_t)(n0 + i)*DIM + t] = acc[i] * lnd[i] + bt;
    }
}

// ---------------- per-node L2 norm -> spread partial sums ----------------
__global__ void k_norm(const float* __restrict__ h2, float* partial) {
    int n = blockIdx.x * 4 + (threadIdx.x >> 6);
    int lane = threadIdx.x & 63;
    float s = 0.f;
#pragma unroll
    for (int j = 0; j < 4; j++) {
        float v = h2[(size_t)n*DIM + lane + j*64];
        s += v * v;
    }
#pragma unroll
    for (int off = 32; off; off >>= 1) s += __shfl_down(s, off, 64);
    if (lane == 0) atomicAdd(&partial[n & 1023], sqrtf(s));
}

__global__ void k_normfin(const float* __restrict__ partial, float* factor) {
    __shared__ float red[256];
    int t = threadIdx.x;
    float s = partial[t] + partial[t + 256] + partial[t + 512] + partial[t + 768];
    red[t] = s;
    __syncthreads();
    for (int o = 128; o; o >>= 1) {
        if (t < o) red[t] += red[t + o];
        __syncthreads();
    }
    if (t == 0) factor[0] = 16.0f / (red[0] / (float)N_NODES);
}

// ---------------- pool: mol_atom_embedding (and first half of mol_embedding) ----------------
__global__ void k_pool(const float* __restrict__ h2, const float* __restrict__ factor,
                       float* out) {
    int b = blockIdx.x, t = threadIdx.x;
    float fac = factor[0];
    float s = 0.f;
    for (int a = 0; a < ATOMS; a++) s += h2[(size_t)(b*ATOMS + a)*DIM + t];
    s *= fac;
    out[(size_t)b*512 + t] = s;                              // mol_embedding[:, :256]
    out[(size_t)BATCH*512 + (size_t)b*DIM + t] = s;          // mol_atom_embedding
}

// ---------------- target_embedding = source_re + target_re ----------------
__global__ void k_target(const int* __restrict__ id_list, const int* __restrict__ id_list_t,
                         const float* __restrict__ mfea, const float* __restrict__ fea_emb,
                         float* tgt) {
    __shared__ float com[MF];
    int b = blockIdx.x, t = threadIdx.x;
    if (t < MF) {
        int i0 = id_list[b], i1 = id_list[BATCH + b];
        int j0 = id_list_t[b], j1 = id_list_t[BATCH + b];
        com[t] = 0.5f * (mfea[(size_t)i0*MF + t] + mfea[(size_t)i1*MF + t])
               + 0.5f * (mfea[(size_t)j0*MF + t] + mfea[(size_t)j1*MF + t]);
    }
    __syncthreads();
    float acc = 0.f;
    for (int f = 0; f < MF; f++) acc += com[f] * fea_emb[f*DIM + t];
    tgt[(size_t)b*DIM + t] = acc;
}

// ---------------- attention block per (s,b): rxn = item + nei_agg ----------------
__global__ void k_attn(const int* __restrict__ id_list, const int* __restrict__ neimat,
                       const float* __restrict__ mfea, const float* __restrict__ fea_emb,
                       const float* __restrict__ att_w, const float* __restrict__ att_b,
                       const float* __restrict__ tgt, float* rxn) {
    __shared__ float mitem[MF];
    __shared__ float u[DIM];
    __shared__ float nm[NUM_NEI * MF];
    __shared__ float vv[MF];
    __shared__ float aw[NUM_NEI];
    int sb = blockIdx.x;              // s*BATCH + b
    int b = sb & (BATCH - 1);
    int t = threadIdx.x;
    int id = id_list[sb];
    if (t < MF) mitem[t] = mfea[(size_t)id*MF + t];
    for (int i = t; i < NUM_NEI * MF; i += 256) {
        int k = i / MF, f = i - k*MF;
        int nid = neimat[(size_t)id*NUM_NEI + k];
        nm[i] = mfea[(size_t)nid*MF + f];
    }
    __syncthreads();
    float item = 0.f;
    for (int f = 0; f < MF; f++) item += mitem[f] * fea_emb[f*DIM + t];
    float tg = tgt[(size_t)b*DIM + t];
    float awt = att_w[t];
    u[t] = item * tg * awt;
    __syncthreads();
    // v[f] = sum_t u[t]*fea_emb[f,t]  (8 waves x 5 f's each)
    int wv = t >> 6, lane = t & 63;
    for (int i = 0; i < 5; i++) {
        int f = wv + 8*i;
        float p = 0.f;
#pragma unroll
        for (int j = 0; j < 4; j++) p += u[lane + 64*j] * fea_emb[f*DIM + lane + 64*j];
#pragma unroll
        for (int off = 32; off; off >>= 1) p += __shfl_down(p, off, 64);
        if (lane == 0) vv[f] = p;
    }
    __syncthreads();
    // logits + softmax over 32 neighbors (first wave, lanes 0..31)
    if (wv == 0) {
        float lg = -1e30f;
        if (lane < NUM_NEI) {
            lg = att_b[0];
            for (int f = 0; f < MF; f++) lg += nm[lane*MF + f] * vv[f];
        }
        float m = lg;
#pragma unroll
        for (int off = 16; off; off >>= 1) m = fmaxf(m, __shfl_xor(m, off, 32));
        float e = (lane < NUM_NEI) ? __expf(lg - m) : 0.f;
        float ssum = e;
#pragma unroll
        for (int off = 16; off; off >>= 1) ssum += __shfl_xor(ssum, off, 32);
        if (lane < NUM_NEI) aw[lane] = e / ssum;
    }
    __syncthreads();
    // w[f] = sum_k a_k * nm[k][f]   (reuse vv)
    if (t < MF) {
        float w = 0.f;
        for (int k = 0; k < NUM_NEI; k++) w += aw[k] * nm[k*MF + t];
        vv[t] = w;
    }
    __syncthreads();
    float na = 0.f;
    for (int f = 0; f < MF; f++) na += vv[f] * fea_emb[f*DIM + t];
    rxn[(size_t)sb*DIM + t] = item + na;
}

// ---------------- final: mol_reaction half + mol_x ----------------
__global__ void k_final(const float* __restrict__ rxn, const float* __restrict__ crosscl_w,
                        const float* __restrict__ crosscl_b, float* out) {
    __shared__ float mre[DIM];
    int b = blockIdx.x, t = threadIdx.x;
    float m = 0.5f * (rxn[(size_t)b*DIM + t] + rxn[(size_t)(BATCH + b)*DIM + t]);
    out[(size_t)b*512 + DIM + t] = m;                        // mol_embedding[:, 256:]
    mre[t] = m;
    __syncthreads();
    float acc = crosscl_b[t];
    for (int uu = 0; uu < DIM; uu++) acc += mre[uu] * crosscl_w[uu*DIM + t];
    out[(size_t)BATCH*768 + (size_t)b*DIM + t] = acc;        // mol_x_embedding
}

extern "C" void kernel_launch(void* const* d_in, const int* in_sizes, int n_in,
                              void* d_out, int out_size, void* d_ws, size_t ws_size,
                              hipStream_t stream) {
    const int*   node_feat = (const int*)d_in[0];
    const int*   edge_src  = (const int*)d_in[1];
    const int*   edge_dst  = (const int*)d_in[2];
    // d_in[3] graph_ids: contiguous 30-atom runs per setup — used implicitly
    const int*   id_list   = (const int*)d_in[4];
    const int*   id_list_t = (const int*)d_in[5];
    const float* all_mfea  = (const float*)d_in[6];
    const int*   neimat    = (const int*)d_in[7];
    const float* W0        = (const float*)d_in[8];
    const float* b0        = (const float*)d_in[9];
    const float* W1        = (const float*)d_in[10];
    const float* b1        = (const float*)d_in[11];
    const float* fea_emb   = (const float*)d_in[12];
    const float* att_w     = (const float*)d_in[13];
    const float* att_b     = (const float*)d_in[14];
    const float* crosscl_w = (const float*)d_in[15];
    const float* crosscl_b = (const float*)d_in[16];
    float* out = (float*)d_out;

    char* ws = (char*)d_ws;
    int*   deg_out = (int*)ws;            ws += (size_t)N_NODES * 4;
    int*   deg_in  = (int*)ws;            ws += (size_t)N_NODES * 4;
    float* partial = (float*)ws;          ws += 1024 * 4;
    float* factor  = (float*)ws;          ws += 256;
    float* agg0    = (float*)ws;          ws += (size_t)N_NODES * 64 * 4;
    float* h       = (float*)ws;          ws += (size_t)N_NODES * DIM * 4;  // h1 then h2
    float* agg1    = (float*)ws;          ws += (size_t)N_NODES * DIM * 4;
    float* tgt     = (float*)ws;          ws += (size_t)BATCH * DIM * 4;
    float* rxn     = (float*)ws;          ws += (size_t)2 * BATCH * DIM * 4;

    // zero: degrees + norm partials + factor (contiguous), agg0, agg1
    hipMemsetAsync(deg_out, 0, (size_t)N_NODES * 8 + 1024 * 4 + 256, stream);
    hipMemsetAsync(agg0, 0, (size_t)N_NODES * 64 * 4, stream);
    hipMemsetAsync(agg1, 0, (size_t)N_NODES * DIM * 4, stream);

    k_deg<<<(N_EDGES + 255) / 256, 256, 0, stream>>>(edge_src, edge_dst, deg_out, deg_in);
    k_scatter0<<<N_EDGES / 4, 256, 0, stream>>>(node_feat, edge_src, edge_dst, deg_out, agg0);
    k_gemm0<<<N_NODES / NPB0, 256, 0, stream>>>(agg0, deg_in, W0, b0, h);
    k_scatter1<<<N_EDGES / 4, 256, 0, stream>>>(h, edge_src, edge_dst, deg_out, agg1);
    k_gemm1<<<N_NODES / NPB1, 256, 0, stream>>>(agg1, deg_in, W1, b1, h);
    k_norm<<<N_NODES / 4, 256, 0, stream>>>(h, partial);
    k_normfin<<<1, 256, 0, stream>>>(partial, factor);
    k_pool<<<BATCH, 256, 0, stream>>>(h, factor, out);
    k_target<<<BATCH, 256, 0, stream>>>(id_list, id_list_t, all_mfea, fea_emb, tgt);
    k_attn<<<2 * BATCH, 256, 0, stream>>>(id_list, neimat, all_mfea, fea_emb,
                                          att_w, att_b, tgt, rxn);
    k_final<<<BATCH, 256, 0, stream>>>(rxn, crosscl_w, crosscl_b, out);
}

// Round 2
// 429.049 us; speedup vs baseline: 1.3462x; 1.3462x over previous
//
#include <hip/hip_runtime.h>
#include <math.h>

#define N_NODES 61440
#define N_EDGES 245760
#define BATCH   2048
#define ATOMS   30
#define F_LEN   64
#define DIM     256
#define NUM_NEI 32
#define MF      40
#define NPB0    16
#define NPB1    16
#define NCHUNK  (N_NODES / 256)   // 240

// ---------------- degree counts ----------------
__global__ void k_deg(const int* __restrict__ esrc, const int* __restrict__ edst,
                      int* deg_out, int* deg_in) {
    int e = blockIdx.x * 256 + threadIdx.x;
    if (e < N_EDGES) {
        atomicAdd(&deg_out[esrc[e]], 1);
        atomicAdd(&deg_in[edst[e]], 1);
    }
}

// ---------------- CSR build: per-chunk scan of deg_in ----------------
__global__ void k_scan_chunk(const int* __restrict__ deg_in, int* row_start, int* chunk_sums) {
    __shared__ int s[256];
    int t = threadIdx.x;
    int n = blockIdx.x * 256 + t;
    int own = deg_in[n];
    s[t] = own;
    __syncthreads();
    for (int o = 1; o < 256; o <<= 1) {
        int v = (t >= o) ? s[t - o] : 0;
        __syncthreads();
        s[t] += v;
        __syncthreads();
    }
    row_start[n] = s[t] - own;           // chunk-local exclusive
    if (t == 255) chunk_sums[blockIdx.x] = s[255];
}

__global__ void k_scan_top(int* chunk_sums, int* chunk_off) {
    __shared__ int s[256];
    int t = threadIdx.x;
    int own = (t < NCHUNK) ? chunk_sums[t] : 0;
    s[t] = own;
    __syncthreads();
    for (int o = 1; o < 256; o <<= 1) {
        int v = (t >= o) ? s[t - o] : 0;
        __syncthreads();
        s[t] += v;
        __syncthreads();
    }
    if (t < NCHUNK) chunk_off[t] = s[t] - own;   // exclusive
}

__global__ void k_add_off(int* row_start, const int* __restrict__ chunk_off, int* cursor) {
    int n = blockIdx.x * 256 + threadIdx.x;
    int v = row_start[n] + chunk_off[n >> 8];
    row_start[n] = v;
    cursor[n] = v;
}

__global__ void k_csr_fill(const int* __restrict__ esrc, const int* __restrict__ edst,
                           int* cursor, int* csr_src) {
    int e = blockIdx.x * 256 + threadIdx.x;
    if (e < N_EDGES) {
        int p = atomicAdd(&cursor[edst[e]], 1);
        csr_src[p] = esrc[e];
    }
}

// ---------------- layer-0 scatter: agg0[dst] += onehot(src)*norm_src ----------------
__global__ void k_scatter0(const int* __restrict__ nf, const int* __restrict__ esrc,
                           const int* __restrict__ edst, const int* __restrict__ deg_out,
                           float* agg0) {
    int e = blockIdx.x * 4 + (threadIdx.x >> 6);
    int lane = threadIdx.x & 63;
    if (e >= N_EDGES) return;
    int s = esrc[e], d = edst[e];
    float ns = rsqrtf((float)max(deg_out[s], 1));
    int n0 = nf[s*4+0], n1 = nf[s*4+1], n2 = nf[s*4+2], n3 = nf[s*4+3];
    int cnt = (n0 == lane) + (n1 == lane) + (n2 == lane) + (n3 == lane);
    if (cnt) atomicAdd(&agg0[d*64 + lane], (float)cnt * ns);
}

// ---------------- gemm0: h1 = relu(norm_dst * (agg0 @ W0) + b0) * norm_src ----------------
__global__ void k_gemm0(const float* __restrict__ agg0, const int* __restrict__ deg_in,
                        const int* __restrict__ deg_out,
                        const float* __restrict__ W0, const float* __restrict__ b0,
                        float* h1) {
    __shared__ float la[NPB0 * 64];
    __shared__ float lnd[NPB0];
    __shared__ float lns[NPB0];
    int n0 = blockIdx.x * NPB0;
    int t = threadIdx.x;
    for (int i = t; i < NPB0 * 64; i += 256) la[i] = agg0[n0*64 + i];
    if (t < NPB0) {
        lnd[t] = rsqrtf((float)max(deg_in[n0 + t], 1));
        lns[t] = rsqrtf((float)max(deg_out[n0 + t], 1));
    }
    __syncthreads();
    float acc[NPB0];
#pragma unroll
    for (int i = 0; i < NPB0; i++) acc[i] = 0.f;
    for (int f = 0; f < 64; f++) {
        float wf = W0[f*DIM + t];
#pragma unroll
        for (int i = 0; i < NPB0; i++) acc[i] += la[i*64 + f] * wf;
    }
    float bt = b0[t];
#pragma unroll
    for (int i = 0; i < NPB0; i++) {
        float z = acc[i] * lnd[i] + bt;
        h1[(size_t)(n0 + i)*DIM + t] = fmaxf(z, 0.f) * lns[i];
    }
}

// ---------------- fused gather + gemm1: h2 = norm_dst*(gather(h1s) @ W1) + b1 ----------------
__global__ void k_gemm1f(const float* __restrict__ h1, const int* __restrict__ row_start,
                         const int* __restrict__ deg_in, const int* __restrict__ csr_src,
                         const float* __restrict__ W1, const float* __restrict__ b1,
                         float* h2) {
    __shared__ float la[NPB1 * DIM];
    __shared__ float lnd[NPB1];
    int n0 = blockIdx.x * NPB1;
    int t = threadIdx.x;
    // gather in-edges for each of NPB1 nodes; thread t owns dim t
#pragma unroll 1
    for (int i = 0; i < NPB1; i++) {
        int n = n0 + i;
        int beg = row_start[n];
        int dcnt = deg_in[n];
        float acc = 0.f;
        for (int e = 0; e < dcnt; e++) {
            int s = csr_src[beg + e];
            acc += h1[(size_t)s*DIM + t];
        }
        la[i*DIM + t] = acc;
    }
    if (t < NPB1) lnd[t] = rsqrtf((float)max(deg_in[n0 + t], 1));
    __syncthreads();
    float acc[NPB1];
#pragma unroll
    for (int i = 0; i < NPB1; i++) acc[i] = 0.f;
    for (int f = 0; f < DIM; f++) {
        float wf = W1[f*DIM + t];
#pragma unroll
        for (int i = 0; i < NPB1; i++) acc[i] += la[i*DIM + f] * wf;
    }
    float bt = b1[t];
#pragma unroll
    for (int i = 0; i < NPB1; i++) {
        h2[(size_t)(n0 + i)*DIM + t] = acc[i] * lnd[i] + bt;
    }
}

// ---------------- per-node L2 norm -> spread partial sums ----------------
__global__ void k_norm(const float* __restrict__ h2, float* partial) {
    int n = blockIdx.x * 4 + (threadIdx.x >> 6);
    int lane = threadIdx.x & 63;
    float s = 0.f;
#pragma unroll
    for (int j = 0; j < 4; j++) {
        float v = h2[(size_t)n*DIM + lane + j*64];
        s += v * v;
    }
#pragma unroll
    for (int off = 32; off; off >>= 1) s += __shfl_down(s, off, 64);
    if (lane == 0) atomicAdd(&partial[n & 1023], sqrtf(s));
}

__global__ void k_normfin(const float* __restrict__ partial, float* factor) {
    __shared__ float red[256];
    int t = threadIdx.x;
    float s = partial[t] + partial[t + 256] + partial[t + 512] + partial[t + 768];
    red[t] = s;
    __syncthreads();
    for (int o = 128; o; o >>= 1) {
        if (t < o) red[t] += red[t + o];
        __syncthreads();
    }
    if (t == 0) factor[0] = 16.0f / (red[0] / (float)N_NODES);
}

// ---------------- pool: mol_atom_embedding (and first half of mol_embedding) ----------------
__global__ void k_pool(const float* __restrict__ h2, const float* __restrict__ factor,
                       float* out) {
    int b = blockIdx.x, t = threadIdx.x;
    float fac = factor[0];
    float s = 0.f;
    for (int a = 0; a < ATOMS; a++) s += h2[(size_t)(b*ATOMS + a)*DIM + t];
    s *= fac;
    out[(size_t)b*512 + t] = s;                              // mol_embedding[:, :256]
    out[(size_t)BATCH*512 + (size_t)b*DIM + t] = s;          // mol_atom_embedding
}

// ---------------- target_embedding = source_re + target_re ----------------
__global__ void k_target(const int* __restrict__ id_list, const int* __restrict__ id_list_t,
                         const float* __restrict__ mfea, const float* __restrict__ fea_emb,
                         float* tgt) {
    __shared__ float com[MF];
    int b = blockIdx.x, t = threadIdx.x;
    if (t < MF) {
        int i0 = id_list[b], i1 = id_list[BATCH + b];
        int j0 = id_list_t[b], j1 = id_list_t[BATCH + b];
        com[t] = 0.5f * (mfea[(size_t)i0*MF + t] + mfea[(size_t)i1*MF + t])
               + 0.5f * (mfea[(size_t)j0*MF + t] + mfea[(size_t)j1*MF + t]);
    }
    __syncthreads();
    float acc = 0.f;
    for (int f = 0; f < MF; f++) acc += com[f] * fea_emb[f*DIM + t];
    tgt[(size_t)b*DIM + t] = acc;
}

// ---------------- attention block per (s,b): rxn = item + nei_agg ----------------
__global__ void k_attn(const int* __restrict__ id_list, const int* __restrict__ neimat,
                       const float* __restrict__ mfea, const float* __restrict__ fea_emb,
                       const float* __restrict__ att_w, const float* __restrict__ att_b,
                       const float* __restrict__ tgt, float* rxn) {
    __shared__ float mitem[MF];
    __shared__ float u[DIM];
    __shared__ float nm[NUM_NEI * MF];
    __shared__ float vv[MF];
    __shared__ float aw[NUM_NEI];
    int sb = blockIdx.x;              // s*BATCH + b
    int b = sb & (BATCH - 1);
    int t = threadIdx.x;
    int id = id_list[sb];
    if (t < MF) mitem[t] = mfea[(size_t)id*MF + t];
    for (int i = t; i < NUM_NEI * MF; i += 256) {
        int k = i / MF, f = i - k*MF;
        int nid = neimat[(size_t)id*NUM_NEI + k];
        nm[i] = mfea[(size_t)nid*MF + f];
    }
    __syncthreads();
    float item = 0.f;
    for (int f = 0; f < MF; f++) item += mitem[f] * fea_emb[f*DIM + t];
    float tg = tgt[(size_t)b*DIM + t];
    float awt = att_w[t];
    u[t] = item * tg * awt;
    __syncthreads();
    // v[f] = sum_t u[t]*fea_emb[f,t]  (8 waves x 5 f's each)
    int wv = t >> 6, lane = t & 63;
    for (int i = 0; i < 5; i++) {
        int f = wv + 8*i;
        float p = 0.f;
#pragma unroll
        for (int j = 0; j < 4; j++) p += u[lane + 64*j] * fea_emb[f*DIM + lane + 64*j];
#pragma unroll
        for (int off = 32; off; off >>= 1) p += __shfl_down(p, off, 64);
        if (lane == 0) vv[f] = p;
    }
    __syncthreads();
    // logits + softmax over 32 neighbors (first wave, lanes 0..31)
    if (wv == 0) {
        float lg = -1e30f;
        if (lane < NUM_NEI) {
            lg = att_b[0];
            for (int f = 0; f < MF; f++) lg += nm[lane*MF + f] * vv[f];
        }
        float m = lg;
#pragma unroll
        for (int off = 16; off; off >>= 1) m = fmaxf(m, __shfl_xor(m, off, 32));
        float e = (lane < NUM_NEI) ? __expf(lg - m) : 0.f;
        float ssum = e;
#pragma unroll
        for (int off = 16; off; off >>= 1) ssum += __shfl_xor(ssum, off, 32);
        if (lane < NUM_NEI) aw[lane] = e / ssum;
    }
    __syncthreads();
    // w[f] = sum_k a_k * nm[k][f]   (reuse vv)
    if (t < MF) {
        float w = 0.f;
        for (int k = 0; k < NUM_NEI; k++) w += aw[k] * nm[k*MF + t];
        vv[t] = w;
    }
    __syncthreads();
    float na = 0.f;
    for (int f = 0; f < MF; f++) na += vv[f] * fea_emb[f*DIM + t];
    rxn[(size_t)sb*DIM + t] = item + na;
}

// ---------------- final: mol_reaction half + mol_x ----------------
__global__ void k_final(const float* __restrict__ rxn, const float* __restrict__ crosscl_w,
                        const float* __restrict__ crosscl_b, float* out) {
    __shared__ float mre[DIM];
    int b = blockIdx.x, t = threadIdx.x;
    float m = 0.5f * (rxn[(size_t)b*DIM + t] + rxn[(size_t)(BATCH + b)*DIM + t]);
    out[(size_t)b*512 + DIM + t] = m;                        // mol_embedding[:, 256:]
    mre[t] = m;
    __syncthreads();
    float acc = crosscl_b[t];
    for (int uu = 0; uu < DIM; uu++) acc += mre[uu] * crosscl_w[uu*DIM + t];
    out[(size_t)BATCH*768 + (size_t)b*DIM + t] = acc;        // mol_x_embedding
}

extern "C" void kernel_launch(void* const* d_in, const int* in_sizes, int n_in,
                              void* d_out, int out_size, void* d_ws, size_t ws_size,
                              hipStream_t stream) {
    const int*   node_feat = (const int*)d_in[0];
    const int*   edge_src  = (const int*)d_in[1];
    const int*   edge_dst  = (const int*)d_in[2];
    const int*   id_list   = (const int*)d_in[4];
    const int*   id_list_t = (const int*)d_in[5];
    const float* all_mfea  = (const float*)d_in[6];
    const int*   neimat    = (const int*)d_in[7];
    const float* W0        = (const float*)d_in[8];
    const float* b0        = (const float*)d_in[9];
    const float* W1        = (const float*)d_in[10];
    const float* b1        = (const float*)d_in[11];
    const float* fea_emb   = (const float*)d_in[12];
    const float* att_w     = (const float*)d_in[13];
    const float* att_b     = (const float*)d_in[14];
    const float* crosscl_w = (const float*)d_in[15];
    const float* crosscl_b = (const float*)d_in[16];
    float* out = (float*)d_out;

    char* ws = (char*)d_ws;
    int*   deg_out   = (int*)ws;          ws += (size_t)N_NODES * 4;
    int*   deg_in    = (int*)ws;          ws += (size_t)N_NODES * 4;
    float* partial   = (float*)ws;        ws += 1024 * 4;
    float* factor    = (float*)ws;        ws += 256;
    int*   row_start = (int*)ws;          ws += (size_t)N_NODES * 4;
    int*   cursor    = (int*)ws;          ws += (size_t)N_NODES * 4;
    int*   csr_srcb  = (int*)ws;          ws += (size_t)N_EDGES * 4;
    int*   chunk_sums= (int*)ws;          ws += NCHUNK * 4;
    int*   chunk_off = (int*)ws;          ws += NCHUNK * 4;
    float* agg0      = (float*)ws;        ws += (size_t)N_NODES * 64 * 4;
    float* h         = (float*)ws;        ws += (size_t)N_NODES * DIM * 4;  // h1s then reused
    float* h2        = (float*)ws;        ws += (size_t)N_NODES * DIM * 4;
    float* tgt       = (float*)ws;        ws += (size_t)BATCH * DIM * 4;
    float* rxn       = (float*)ws;        ws += (size_t)2 * BATCH * DIM * 4;

    // zero: degrees + norm partials + factor (contiguous), agg0
    hipMemsetAsync(deg_out, 0, (size_t)N_NODES * 8 + 1024 * 4 + 256, stream);
    hipMemsetAsync(agg0, 0, (size_t)N_NODES * 64 * 4, stream);

    k_deg<<<(N_EDGES + 255) / 256, 256, 0, stream>>>(edge_src, edge_dst, deg_out, deg_in);
    // CSR build (by dst)
    k_scan_chunk<<<NCHUNK, 256, 0, stream>>>(deg_in, row_start, chunk_sums);
    k_scan_top<<<1, 256, 0, stream>>>(chunk_sums, chunk_off);
    k_add_off<<<N_NODES / 256, 256, 0, stream>>>(row_start, chunk_off, cursor);
    k_csr_fill<<<(N_EDGES + 255) / 256, 256, 0, stream>>>(edge_src, edge_dst, cursor, csr_srcb);
    // layer 0
    k_scatter0<<<N_EDGES / 4, 256, 0, stream>>>(node_feat, edge_src, edge_dst, deg_out, agg0);
    k_gemm0<<<N_NODES / NPB0, 256, 0, stream>>>(agg0, deg_in, deg_out, W0, b0, h);
    // layer 1 (fused gather + GEMM)
    k_gemm1f<<<N_NODES / NPB1, 256, 0, stream>>>(h, row_start, deg_in, csr_srcb, W1, b1, h2);
    k_norm<<<N_NODES / 4, 256, 0, stream>>>(h2, partial);
    k_normfin<<<1, 256, 0, stream>>>(partial, factor);
    k_pool<<<BATCH, 256, 0, stream>>>(h2, factor, out);
    k_target<<<BATCH, 256, 0, stream>>>(id_list, id_list_t, all_mfea, fea_emb, tgt);
    k_attn<<<2 * BATCH, 256, 0, stream>>>(id_list, neimat, all_mfea, fea_emb,
                                          att_w, att_b, tgt, rxn);
    k_final<<<BATCH, 256, 0, stream>>>(rxn, crosscl_w, crosscl_b, out);
}

// Round 3
// 268.392 us; speedup vs baseline: 2.1521x; 1.5986x over previous
//
#include <hip/hip_runtime.h>
#include <math.h>

#define N_NODES 61440
#define N_EDGES 245760
#define BATCH   2048
#define ATOMS   30
#define F_LEN   64
#define DIM     256
#define NUM_NEI 32
#define MF      40
#define NCHUNK  (N_NODES / 256)   // 240
#define ECAP    512

typedef __attribute__((ext_vector_type(8))) short s8v;
typedef __attribute__((ext_vector_type(4))) float f4v;

__device__ __forceinline__ unsigned short f2bf(float x) {
    union { float f; unsigned u; } c; c.f = x;
    unsigned r = (c.u + 0x7FFFu + ((c.u >> 16) & 1u)) >> 16;
    return (unsigned short)r;
}
__device__ __forceinline__ float bf2f(unsigned short u) {
    union { unsigned u; float f; } c; c.u = ((unsigned)u) << 16;
    return c.f;
}

// ---------------- degree counts ----------------
__global__ void k_deg(const int* __restrict__ esrc, const int* __restrict__ edst,
                      int* deg_out, int* deg_in) {
    int e = blockIdx.x * 256 + threadIdx.x;
    if (e < N_EDGES) {
        atomicAdd(&deg_out[esrc[e]], 1);
        atomicAdd(&deg_in[edst[e]], 1);
    }
}

// ---------------- CSR build ----------------
__global__ void k_scan_chunk(const int* __restrict__ deg_in, int* row_start, int* chunk_sums) {
    __shared__ int s[256];
    int t = threadIdx.x;
    int n = blockIdx.x * 256 + t;
    int own = deg_in[n];
    s[t] = own;
    __syncthreads();
    for (int o = 1; o < 256; o <<= 1) {
        int v = (t >= o) ? s[t - o] : 0;
        __syncthreads();
        s[t] += v;
        __syncthreads();
    }
    row_start[n] = s[t] - own;
    if (t == 255) chunk_sums[blockIdx.x] = s[255];
}

__global__ void k_scan_top(int* chunk_sums, int* chunk_off) {
    __shared__ int s[256];
    int t = threadIdx.x;
    int own = (t < NCHUNK) ? chunk_sums[t] : 0;
    s[t] = own;
    __syncthreads();
    for (int o = 1; o < 256; o <<= 1) {
        int v = (t >= o) ? s[t - o] : 0;
        __syncthreads();
        s[t] += v;
        __syncthreads();
    }
    if (t < NCHUNK) chunk_off[t] = s[t] - own;
}

__global__ void k_add_off(int* row_start, const int* __restrict__ chunk_off, int* cursor) {
    int n = blockIdx.x * 256 + threadIdx.x;
    int v = row_start[n] + chunk_off[n >> 8];
    row_start[n] = v;
    cursor[n] = v;
}

__global__ void k_csr_fill(const int* __restrict__ esrc, const int* __restrict__ edst,
                           int* cursor, int* csr_src) {
    int e = blockIdx.x * 256 + threadIdx.x;
    if (e < N_EDGES) {
        int p = atomicAdd(&cursor[edst[e]], 1);
        csr_src[p] = esrc[e];
    }
}

// ---------------- weight prep: bf16 transposed copies ----------------
__global__ void k_prepw(const float* __restrict__ W0, const float* __restrict__ W1,
                        unsigned short* w0bt, unsigned short* w1bt) {
    int n = blockIdx.x, k = threadIdx.x;
    w1bt[(size_t)n * 256 + k] = f2bf(W1[(size_t)k * 256 + n]);
    if (k < 64) w0bt[(size_t)n * 64 + k] = f2bf(W0[(size_t)k * 256 + n]);
}

// ---------------- fused layer-0: CSR gather one-hot + MFMA gemm -> h1 bf16 ----------------
__global__ __launch_bounds__(256) void k_gcn0(
    const int* __restrict__ nf, const int* __restrict__ row_start,
    const int* __restrict__ csr_src, const int* __restrict__ deg_in,
    const int* __restrict__ deg_out, const unsigned short* __restrict__ w0bt,
    const float* __restrict__ b0, unsigned short* __restrict__ h1b) {
    __shared__ float la0[32 * 68];
    __shared__ int4  enf[ECAP];
    __shared__ float ens[ECAP];
    __shared__ int   rs[33];
    __shared__ float lnd[32], lns[32];
    __shared__ float b0c[256];
    int n0 = blockIdx.x * 32;
    int t = threadIdx.x;
    if (t < 33) {
        int n = n0 + t;
        rs[t] = (n < N_NODES) ? row_start[n] : N_EDGES;
    }
    if (t < 32) {
        lnd[t] = rsqrtf((float)max(deg_in[n0 + t], 1));
        lns[t] = rsqrtf((float)max(deg_out[n0 + t], 1));
    }
    b0c[t] = b0[t];
    __syncthreads();
    int beg0 = rs[0];
    int tot = rs[32] - beg0; if (tot > ECAP) tot = ECAP;
    for (int e = t; e < tot; e += 256) {
        int s = csr_src[beg0 + e];
        enf[e] = ((const int4*)nf)[s];
        ens[e] = rsqrtf((float)max(deg_out[s], 1));
    }
    __syncthreads();
    {   // build la0[row][64] one-hot aggregate
        int row = t >> 3, kc = (t & 7) * 8;
        float a[8];
#pragma unroll
        for (int j = 0; j < 8; j++) a[j] = 0.f;
        int lo = rs[row] - beg0, hi = rs[row + 1] - beg0;
        if (hi > tot) hi = tot;
        for (int e = lo; e < hi; e++) {
            int4 f = enf[e]; float w = ens[e];
#pragma unroll
            for (int j = 0; j < 8; j++) {
                int k = kc + j;
                a[j] += w * (float)((f.x == k) + (f.y == k) + (f.z == k) + (f.w == k));
            }
        }
#pragma unroll
        for (int j = 0; j < 8; j++) la0[row * 68 + kc + j] = a[j];
    }
    __syncthreads();
    int lane = t & 63, wv = t >> 6;
    int ln = lane & 15, lg = lane >> 4;
    f4v acc[2][4];
#pragma unroll
    for (int mi = 0; mi < 2; mi++)
#pragma unroll
        for (int ni = 0; ni < 4; ni++) acc[mi][ni] = (f4v)0.f;
#pragma unroll
    for (int kst = 0; kst < 2; kst++) {
        s8v afr[2];
#pragma unroll
        for (int mi = 0; mi < 2; mi++) {
            const float* p = &la0[(mi * 16 + ln) * 68 + kst * 32 + lg * 8];
            f4v lo = *(const f4v*)p;
            f4v hi = *(const f4v*)(p + 4);
            s8v a;
#pragma unroll
            for (int j = 0; j < 4; j++) { a[j] = (short)f2bf(lo[j]); a[4 + j] = (short)f2bf(hi[j]); }
            afr[mi] = a;
        }
#pragma unroll
        for (int ni = 0; ni < 4; ni++) {
            int n = wv * 64 + ni * 16 + ln;
            s8v b = *(const s8v*)&w0bt[(size_t)n * 64 + kst * 32 + lg * 8];
            acc[0][ni] = __builtin_amdgcn_mfma_f32_16x16x32_bf16(afr[0], b, acc[0][ni], 0, 0, 0);
            acc[1][ni] = __builtin_amdgcn_mfma_f32_16x16x32_bf16(afr[1], b, acc[1][ni], 0, 0, 0);
        }
    }
#pragma unroll
    for (int mi = 0; mi < 2; mi++)
#pragma unroll
        for (int ni = 0; ni < 4; ni++) {
            int n = wv * 64 + ni * 16 + ln;
            float bb = b0c[n];
#pragma unroll
            for (int r = 0; r < 4; r++) {
                int m = mi * 16 + lg * 4 + r;
                float z = acc[mi][ni][r] * lnd[m] + bb;
                z = fmaxf(z, 0.f) * lns[m];
                h1b[(size_t)(n0 + m) * 256 + n] = f2bf(z);
            }
        }
}

// ---------------- fused layer-1: CSR gather + MFMA gemm + norm reduce -> h2 fp32 ----------------
__global__ __launch_bounds__(256) void k_gcn1(
    const unsigned short* __restrict__ h1b, const int* __restrict__ row_start,
    const int* __restrict__ csr_src, const int* __restrict__ deg_in,
    const unsigned short* __restrict__ w1bt, const float* __restrict__ b1,
    float* __restrict__ h2, float* __restrict__ partial) {
    __shared__ unsigned short lab[32 * 264];
    __shared__ int   ecache[ECAP];
    __shared__ int   rs[33];
    __shared__ float lnd[32];
    __shared__ float b1c[256];
    __shared__ float nsq[32];
    int n0 = blockIdx.x * 32;
    int t = threadIdx.x;
    if (t < 33) {
        int n = n0 + t;
        rs[t] = (n < N_NODES) ? row_start[n] : N_EDGES;
    }
    if (t < 32) {
        lnd[t] = rsqrtf((float)max(deg_in[n0 + t], 1));
        nsq[t] = 0.f;
    }
    b1c[t] = b1[t];
    __syncthreads();
    int beg0 = rs[0];
    int tot = rs[32] - beg0; if (tot > ECAP) tot = ECAP;
    for (int e = t; e < tot; e += 256) ecache[e] = csr_src[beg0 + e];
    __syncthreads();
    // gather: thread t owns column t
#pragma unroll 1
    for (int i = 0; i < 32; i++) {
        int lo = rs[i] - beg0, hi = rs[i + 1] - beg0;
        if (hi > tot) hi = tot;
        float acc = 0.f;
        for (int e = lo; e < hi; e++) {
            int s = ecache[e];
            acc += bf2f(h1b[(size_t)s * 256 + t]);
        }
        lab[i * 264 + t] = f2bf(acc);
    }
    __syncthreads();
    int lane = t & 63, wv = t >> 6;
    int ln = lane & 15, lg = lane >> 4;
    f4v acc[2][4];
#pragma unroll
    for (int mi = 0; mi < 2; mi++)
#pragma unroll
        for (int ni = 0; ni < 4; ni++) acc[mi][ni] = (f4v)0.f;
#pragma unroll 2
    for (int kst = 0; kst < 8; kst++) {
        s8v afr[2];
#pragma unroll
        for (int mi = 0; mi < 2; mi++)
            afr[mi] = *(const s8v*)&lab[(mi * 16 + ln) * 264 + kst * 32 + lg * 8];
#pragma unroll
        for (int ni = 0; ni < 4; ni++) {
            int n = wv * 64 + ni * 16 + ln;
            s8v b = *(const s8v*)&w1bt[(size_t)n * 256 + kst * 32 + lg * 8];
            acc[0][ni] = __builtin_amdgcn_mfma_f32_16x16x32_bf16(afr[0], b, acc[0][ni], 0, 0, 0);
            acc[1][ni] = __builtin_amdgcn_mfma_f32_16x16x32_bf16(afr[1], b, acc[1][ni], 0, 0, 0);
        }
    }
    float sm[2][4];
#pragma unroll
    for (int mi = 0; mi < 2; mi++)
#pragma unroll
        for (int r = 0; r < 4; r++) sm[mi][r] = 0.f;
#pragma unroll
    for (int mi = 0; mi < 2; mi++)
#pragma unroll
        for (int ni = 0; ni < 4; ni++) {
            int n = wv * 64 + ni * 16 + ln;
            float bb = b1c[n];
#pragma unroll
            for (int r = 0; r < 4; r++) {
                int m = mi * 16 + lg * 4 + r;
                float z = acc[mi][ni][r] * lnd[m] + bb;
                h2[(size_t)(n0 + m) * 256 + n] = z;
                sm[mi][r] += z * z;
            }
        }
#pragma unroll
    for (int mi = 0; mi < 2; mi++)
#pragma unroll
        for (int r = 0; r < 4; r++) {
            float v = sm[mi][r];
            v += __shfl_xor(v, 1);
            v += __shfl_xor(v, 2);
            v += __shfl_xor(v, 4);
            v += __shfl_xor(v, 8);
            if (ln == 0) atomicAdd(&nsq[mi * 16 + lg * 4 + r], v);
        }
    __syncthreads();
    if (t < 32) atomicAdd(&partial[(n0 + t) & 1023], sqrtf(nsq[t]));
}

// ---------------- norm finish ----------------
__global__ void k_normfin(const float* __restrict__ partial, float* factor) {
    __shared__ float red[256];
    int t = threadIdx.x;
    float s = partial[t] + partial[t + 256] + partial[t + 512] + partial[t + 768];
    red[t] = s;
    __syncthreads();
    for (int o = 128; o; o >>= 1) {
        if (t < o) red[t] += red[t + o];
        __syncthreads();
    }
    if (t == 0) factor[0] = 16.0f / (red[0] / (float)N_NODES);
}

// ---------------- pool ----------------
__global__ void k_pool(const float* __restrict__ h2, const float* __restrict__ factor,
                       float* out) {
    int b = blockIdx.x, t = threadIdx.x;
    float fac = factor[0];
    float s = 0.f;
    for (int a = 0; a < ATOMS; a++) s += h2[(size_t)(b * ATOMS + a) * DIM + t];
    s *= fac;
    out[(size_t)b * 512 + t] = s;
    out[(size_t)BATCH * 512 + (size_t)b * DIM + t] = s;
}

// ---------------- target embedding ----------------
__global__ void k_target(const int* __restrict__ id_list, const int* __restrict__ id_list_t,
                         const float* __restrict__ mfea, const float* __restrict__ fea_emb,
                         float* tgt) {
    __shared__ float com[MF];
    int b = blockIdx.x, t = threadIdx.x;
    if (t < MF) {
        int i0 = id_list[b], i1 = id_list[BATCH + b];
        int j0 = id_list_t[b], j1 = id_list_t[BATCH + b];
        com[t] = 0.5f * (mfea[(size_t)i0 * MF + t] + mfea[(size_t)i1 * MF + t])
               + 0.5f * (mfea[(size_t)j0 * MF + t] + mfea[(size_t)j1 * MF + t]);
    }
    __syncthreads();
    float acc = 0.f;
    for (int f = 0; f < MF; f++) acc += com[f] * fea_emb[f * DIM + t];
    tgt[(size_t)b * DIM + t] = acc;
}

// ---------------- attention per (s,b) ----------------
__global__ void k_attn(const int* __restrict__ id_list, const int* __restrict__ neimat,
                       const float* __restrict__ mfea, const float* __restrict__ fea_emb,
                       const float* __restrict__ att_w, const float* __restrict__ att_b,
                       const float* __restrict__ tgt, float* rxn) {
    __shared__ float mitem[MF];
    __shared__ float u[DIM];
    __shared__ float nm[NUM_NEI * MF];
    __shared__ float vv[MF];
    __shared__ float aw[NUM_NEI];
    int sb = blockIdx.x;
    int b = sb & (BATCH - 1);
    int t = threadIdx.x;
    int id = id_list[sb];
    if (t < MF) mitem[t] = mfea[(size_t)id * MF + t];
    for (int i = t; i < NUM_NEI * MF; i += 256) {
        int k = i / MF, f = i - k * MF;
        int nid = neimat[(size_t)id * NUM_NEI + k];
        nm[i] = mfea[(size_t)nid * MF + f];
    }
    __syncthreads();
    float item = 0.f;
    for (int f = 0; f < MF; f++) item += mitem[f] * fea_emb[f * DIM + t];
    float tg = tgt[(size_t)b * DIM + t];
    float awt = att_w[t];
    u[t] = item * tg * awt;
    __syncthreads();
    int wv = t >> 6, lane = t & 63;
    for (int i = 0; i < 5; i++) {
        int f = wv + 8 * i;
        float p = 0.f;
#pragma unroll
        for (int j = 0; j < 4; j++) p += u[lane + 64 * j] * fea_emb[f * DIM + lane + 64 * j];
#pragma unroll
        for (int off = 32; off; off >>= 1) p += __shfl_down(p, off, 64);
        if (lane == 0) vv[f] = p;
    }
    __syncthreads();
    if (wv == 0) {
        float lg = -1e30f;
        if (lane < NUM_NEI) {
            lg = att_b[0];
            for (int f = 0; f < MF; f++) lg += nm[lane * MF + f] * vv[f];
        }
        float m = lg;
#pragma unroll
        for (int off = 16; off; off >>= 1) m = fmaxf(m, __shfl_xor(m, off, 32));
        float e = (lane < NUM_NEI) ? __expf(lg - m) : 0.f;
        float ssum = e;
#pragma unroll
        for (int off = 16; off; off >>= 1) ssum += __shfl_xor(ssum, off, 32);
        if (lane < NUM_NEI) aw[lane] = e / ssum;
    }
    __syncthreads();
    if (t < MF) {
        float w = 0.f;
        for (int k = 0; k < NUM_NEI; k++) w += aw[k] * nm[k * MF + t];
        vv[t] = w;
    }
    __syncthreads();
    float na = 0.f;
    for (int f = 0; f < MF; f++) na += vv[f] * fea_emb[f * DIM + t];
    rxn[(size_t)sb * DIM + t] = item + na;
}

// ---------------- final ----------------
__global__ void k_final(const float* __restrict__ rxn, const float* __restrict__ crosscl_w,
                        const float* __restrict__ crosscl_b, float* out) {
    __shared__ float mre[DIM];
    int b = blockIdx.x, t = threadIdx.x;
    float m = 0.5f * (rxn[(size_t)b * DIM + t] + rxn[(size_t)(BATCH + b) * DIM + t]);
    out[(size_t)b * 512 + DIM + t] = m;
    mre[t] = m;
    __syncthreads();
    float acc = crosscl_b[t];
    for (int uu = 0; uu < DIM; uu++) acc += mre[uu] * crosscl_w[uu * DIM + t];
    out[(size_t)BATCH * 768 + (size_t)b * DIM + t] = acc;
}

extern "C" void kernel_launch(void* const* d_in, const int* in_sizes, int n_in,
                              void* d_out, int out_size, void* d_ws, size_t ws_size,
                              hipStream_t stream) {
    const int*   node_feat = (const int*)d_in[0];
    const int*   edge_src  = (const int*)d_in[1];
    const int*   edge_dst  = (const int*)d_in[2];
    const int*   id_list   = (const int*)d_in[4];
    const int*   id_list_t = (const int*)d_in[5];
    const float* all_mfea  = (const float*)d_in[6];
    const int*   neimat    = (const int*)d_in[7];
    const float* W0        = (const float*)d_in[8];
    const float* b0        = (const float*)d_in[9];
    const float* W1        = (const float*)d_in[10];
    const float* b1        = (const float*)d_in[11];
    const float* fea_emb   = (const float*)d_in[12];
    const float* att_w     = (const float*)d_in[13];
    const float* att_b     = (const float*)d_in[14];
    const float* crosscl_w = (const float*)d_in[15];
    const float* crosscl_b = (const float*)d_in[16];
    float* out = (float*)d_out;

    char* ws = (char*)d_ws;
    int*   deg_out   = (int*)ws;            ws += (size_t)N_NODES * 4;
    int*   deg_in    = (int*)ws;            ws += (size_t)N_NODES * 4;
    float* partial   = (float*)ws;          ws += 1024 * 4;
    float* factor    = (float*)ws;          ws += 256;
    int*   row_start = (int*)ws;            ws += (size_t)N_NODES * 4;
    int*   cursor    = (int*)ws;            ws += (size_t)N_NODES * 4;
    int*   csr_srcb  = (int*)ws;            ws += (size_t)N_EDGES * 4;
    int*   chunk_sums= (int*)ws;            ws += NCHUNK * 4;
    int*   chunk_off = (int*)ws;            ws += NCHUNK * 4;
    unsigned short* w0bt = (unsigned short*)ws; ws += (size_t)256 * 64 * 2;
    unsigned short* w1bt = (unsigned short*)ws; ws += (size_t)256 * 256 * 2;
    unsigned short* h1b  = (unsigned short*)ws; ws += (size_t)N_NODES * DIM * 2;
    float* h2        = (float*)ws;          ws += (size_t)N_NODES * DIM * 4;
    float* tgt       = (float*)ws;          ws += (size_t)BATCH * DIM * 4;
    float* rxn       = (float*)ws;          ws += (size_t)2 * BATCH * DIM * 4;

    hipMemsetAsync(deg_out, 0, (size_t)N_NODES * 8 + 1024 * 4 + 256, stream);

    k_deg<<<(N_EDGES + 255) / 256, 256, 0, stream>>>(edge_src, edge_dst, deg_out, deg_in);
    k_scan_chunk<<<NCHUNK, 256, 0, stream>>>(deg_in, row_start, chunk_sums);
    k_scan_top<<<1, 256, 0, stream>>>(chunk_sums, chunk_off);
    k_add_off<<<N_NODES / 256, 256, 0, stream>>>(row_start, chunk_off, cursor);
    k_csr_fill<<<(N_EDGES + 255) / 256, 256, 0, stream>>>(edge_src, edge_dst, cursor, csr_srcb);
    k_prepw<<<256, 256, 0, stream>>>(W0, W1, w0bt, w1bt);

    k_gcn0<<<N_NODES / 32, 256, 0, stream>>>(node_feat, row_start, csr_srcb, deg_in,
                                             deg_out, w0bt, b0, h1b);
    k_gcn1<<<N_NODES / 32, 256, 0, stream>>>(h1b, row_start, csr_srcb, deg_in,
                                             w1bt, b1, h2, partial);
    k_normfin<<<1, 256, 0, stream>>>(partial, factor);
    k_pool<<<BATCH, 256, 0, stream>>>(h2, factor, out);
    k_target<<<BATCH, 256, 0, stream>>>(id_list, id_list_t, all_mfea, fea_emb, tgt);
    k_attn<<<2 * BATCH, 256, 0, stream>>>(id_list, neimat, all_mfea, fea_emb,
                                          att_w, att_b, tgt, rxn);
    k_final<<<BATCH, 256, 0, stream>>>(rxn, crosscl_w, crosscl_b, out);
}

// Round 4
// 207.433 us; speedup vs baseline: 2.7845x; 1.2939x over previous
//
#include <hip/hip_runtime.h>
#include <math.h>

#define N_NODES 61440
#define N_EDGES 245760
#define BATCH   2048
#define ATOMS   30
#define F_LEN   64
#define DIM     256
#define NUM_NEI 32
#define MF      40
#define NCHUNK  (N_NODES / 256)   // 240
#define ECAP    512

typedef __attribute__((ext_vector_type(8))) short s8v;
typedef __attribute__((ext_vector_type(4))) float f4v;

__device__ __forceinline__ unsigned short f2bf(float x) {
    union { float f; unsigned u; } c; c.f = x;
    unsigned r = (c.u + 0x7FFFu + ((c.u >> 16) & 1u)) >> 16;
    return (unsigned short)r;
}
__device__ __forceinline__ float bf2f(unsigned short u) {
    union { unsigned u; float f; } c; c.u = ((unsigned)u) << 16;
    return c.f;
}

// ---------------- degree counts ----------------
__global__ void k_deg(const int* __restrict__ esrc, const int* __restrict__ edst,
                      int* deg_out, int* deg_in) {
    int e = blockIdx.x * 256 + threadIdx.x;
    if (e < N_EDGES) {
        atomicAdd(&deg_out[esrc[e]], 1);
        atomicAdd(&deg_in[edst[e]], 1);
    }
}

// ---------------- CSR build ----------------
__global__ void k_scan_chunk(const int* __restrict__ deg_in, int* row_start, int* chunk_sums) {
    __shared__ int s[256];
    int t = threadIdx.x;
    int n = blockIdx.x * 256 + t;
    int own = deg_in[n];
    s[t] = own;
    __syncthreads();
    for (int o = 1; o < 256; o <<= 1) {
        int v = (t >= o) ? s[t - o] : 0;
        __syncthreads();
        s[t] += v;
        __syncthreads();
    }
    row_start[n] = s[t] - own;
    if (t == 255) chunk_sums[blockIdx.x] = s[255];
}

__global__ void k_scan_top(int* chunk_sums, int* chunk_off) {
    __shared__ int s[256];
    int t = threadIdx.x;
    int own = (t < NCHUNK) ? chunk_sums[t] : 0;
    s[t] = own;
    __syncthreads();
    for (int o = 1; o < 256; o <<= 1) {
        int v = (t >= o) ? s[t - o] : 0;
        __syncthreads();
        s[t] += v;
        __syncthreads();
    }
    if (t < NCHUNK) chunk_off[t] = s[t] - own;
}

__global__ void k_add_off(int* row_start, const int* __restrict__ chunk_off, int* cursor) {
    int n = blockIdx.x * 256 + threadIdx.x;
    int v = row_start[n] + chunk_off[n >> 8];
    row_start[n] = v;
    cursor[n] = v;
}

__global__ void k_csr_fill(const int* __restrict__ esrc, const int* __restrict__ edst,
                           int* cursor, int* csr_src) {
    int e = blockIdx.x * 256 + threadIdx.x;
    if (e < N_EDGES) {
        int p = atomicAdd(&cursor[edst[e]], 1);
        csr_src[p] = esrc[e];
    }
}

// ---------------- weight prep: bf16 transposed copies ----------------
__global__ void k_prepw(const float* __restrict__ W0, const float* __restrict__ W1,
                        unsigned short* w0bt, unsigned short* w1bt) {
    int n = blockIdx.x, k = threadIdx.x;
    w1bt[(size_t)n * 256 + k] = f2bf(W1[(size_t)k * 256 + n]);
    if (k < 64) w0bt[(size_t)n * 64 + k] = f2bf(W0[(size_t)k * 256 + n]);
}

// ---------------- fused layer-0: CSR gather one-hot + MFMA gemm -> h1 bf16 ----------------
__global__ __launch_bounds__(256) void k_gcn0(
    const int* __restrict__ nf, const int* __restrict__ row_start,
    const int* __restrict__ csr_src, const int* __restrict__ deg_in,
    const int* __restrict__ deg_out, const unsigned short* __restrict__ w0bt,
    const float* __restrict__ b0, unsigned short* __restrict__ h1b) {
    __shared__ float la0[32 * 68];
    __shared__ int4  enf[ECAP];
    __shared__ float ens[ECAP];
    __shared__ int   rs[33];
    __shared__ float lnd[32], lns[32];
    __shared__ float b0c[256];
    int n0 = blockIdx.x * 32;
    int t = threadIdx.x;
    if (t < 33) {
        int n = n0 + t;
        rs[t] = (n < N_NODES) ? row_start[n] : N_EDGES;
    }
    if (t < 32) {
        lnd[t] = rsqrtf((float)max(deg_in[n0 + t], 1));
        lns[t] = rsqrtf((float)max(deg_out[n0 + t], 1));
    }
    b0c[t] = b0[t];
    __syncthreads();
    int beg0 = rs[0];
    int tot = rs[32] - beg0; if (tot > ECAP) tot = ECAP;
    for (int e = t; e < tot; e += 256) {
        int s = csr_src[beg0 + e];
        enf[e] = ((const int4*)nf)[s];
        ens[e] = rsqrtf((float)max(deg_out[s], 1));
    }
    __syncthreads();
    {   // build la0[row][64] one-hot aggregate
        int row = t >> 3, kc = (t & 7) * 8;
        float a[8];
#pragma unroll
        for (int j = 0; j < 8; j++) a[j] = 0.f;
        int lo = rs[row] - beg0, hi = rs[row + 1] - beg0;
        if (hi > tot) hi = tot;
        for (int e = lo; e < hi; e++) {
            int4 f = enf[e]; float w = ens[e];
#pragma unroll
            for (int j = 0; j < 8; j++) {
                int k = kc + j;
                a[j] += w * (float)((f.x == k) + (f.y == k) + (f.z == k) + (f.w == k));
            }
        }
#pragma unroll
        for (int j = 0; j < 8; j++) la0[row * 68 + kc + j] = a[j];
    }
    __syncthreads();
    int lane = t & 63, wv = t >> 6;
    int ln = lane & 15, lg = lane >> 4;
    f4v acc[2][4];
#pragma unroll
    for (int mi = 0; mi < 2; mi++)
#pragma unroll
        for (int ni = 0; ni < 4; ni++) acc[mi][ni] = (f4v)0.f;
#pragma unroll
    for (int kst = 0; kst < 2; kst++) {
        s8v afr[2];
#pragma unroll
        for (int mi = 0; mi < 2; mi++) {
            const float* p = &la0[(mi * 16 + ln) * 68 + kst * 32 + lg * 8];
            f4v lo = *(const f4v*)p;
            f4v hi = *(const f4v*)(p + 4);
            s8v a;
#pragma unroll
            for (int j = 0; j < 4; j++) { a[j] = (short)f2bf(lo[j]); a[4 + j] = (short)f2bf(hi[j]); }
            afr[mi] = a;
        }
#pragma unroll
        for (int ni = 0; ni < 4; ni++) {
            int n = wv * 64 + ni * 16 + ln;
            s8v b = *(const s8v*)&w0bt[(size_t)n * 64 + kst * 32 + lg * 8];
            acc[0][ni] = __builtin_amdgcn_mfma_f32_16x16x32_bf16(afr[0], b, acc[0][ni], 0, 0, 0);
            acc[1][ni] = __builtin_amdgcn_mfma_f32_16x16x32_bf16(afr[1], b, acc[1][ni], 0, 0, 0);
        }
    }
#pragma unroll
    for (int mi = 0; mi < 2; mi++)
#pragma unroll
        for (int ni = 0; ni < 4; ni++) {
            int n = wv * 64 + ni * 16 + ln;
            float bb = b0c[n];
#pragma unroll
            for (int r = 0; r < 4; r++) {
                int m = mi * 16 + lg * 4 + r;
                float z = acc[mi][ni][r] * lnd[m] + bb;
                z = fmaxf(z, 0.f) * lns[m];
                h1b[(size_t)(n0 + m) * 256 + n] = f2bf(z);
            }
        }
}

// ---------------- fused layer-1: CSR gather + MFMA gemm + norm reduce -> h2 fp32 ----------------
__global__ __launch_bounds__(256) void k_gcn1(
    const unsigned short* __restrict__ h1b, const int* __restrict__ row_start,
    const int* __restrict__ csr_src, const int* __restrict__ deg_in,
    const unsigned short* __restrict__ w1bt, const float* __restrict__ b1,
    float* __restrict__ h2, float* __restrict__ partial) {
    __shared__ unsigned short lab[32 * 264];
    __shared__ int   ecache[ECAP];
    __shared__ int   rs[33];
    __shared__ float lnd[32];
    __shared__ float b1c[256];
    __shared__ float nsq[32];
    int n0 = blockIdx.x * 32;
    int t = threadIdx.x;
    if (t < 33) {
        int n = n0 + t;
        rs[t] = (n < N_NODES) ? row_start[n] : N_EDGES;
    }
    if (t < 32) {
        lnd[t] = rsqrtf((float)max(deg_in[n0 + t], 1));
        nsq[t] = 0.f;
    }
    b1c[t] = b1[t];
    __syncthreads();
    int beg0 = rs[0];
    int tot = rs[32] - beg0; if (tot > ECAP) tot = ECAP;
    for (int e = t; e < tot; e += 256) ecache[e] = csr_src[beg0 + e];
    __syncthreads();
    // gather: 8 rows in parallel, each thread owns 8 contiguous columns (16B loads)
    {
        int gr = t >> 5;             // row within group of 8
        int gc = (t & 31) * 8;       // column base
#pragma unroll 1
        for (int ri = 0; ri < 4; ri++) {
            int i = ri * 8 + gr;
            int lo = rs[i] - beg0, hi = rs[i + 1] - beg0;
            if (hi > tot) hi = tot;
            float a[8];
#pragma unroll
            for (int j = 0; j < 8; j++) a[j] = 0.f;
            for (int e = lo; e < hi; e++) {
                int s = ecache[e];
                s8v v = *(const s8v*)&h1b[(size_t)s * 256 + gc];
#pragma unroll
                for (int j = 0; j < 8; j++) a[j] += bf2f((unsigned short)v[j]);
            }
            s8v ov;
#pragma unroll
            for (int j = 0; j < 8; j++) ov[j] = (short)f2bf(a[j]);
            *(s8v*)&lab[i * 264 + gc] = ov;
        }
    }
    __syncthreads();
    int lane = t & 63, wv = t >> 6;
    int ln = lane & 15, lg = lane >> 4;
    f4v acc[2][4];
#pragma unroll
    for (int mi = 0; mi < 2; mi++)
#pragma unroll
        for (int ni = 0; ni < 4; ni++) acc[mi][ni] = (f4v)0.f;
#pragma unroll 2
    for (int kst = 0; kst < 8; kst++) {
        s8v afr[2];
#pragma unroll
        for (int mi = 0; mi < 2; mi++)
            afr[mi] = *(const s8v*)&lab[(mi * 16 + ln) * 264 + kst * 32 + lg * 8];
#pragma unroll
        for (int ni = 0; ni < 4; ni++) {
            int n = wv * 64 + ni * 16 + ln;
            s8v b = *(const s8v*)&w1bt[(size_t)n * 256 + kst * 32 + lg * 8];
            acc[0][ni] = __builtin_amdgcn_mfma_f32_16x16x32_bf16(afr[0], b, acc[0][ni], 0, 0, 0);
            acc[1][ni] = __builtin_amdgcn_mfma_f32_16x16x32_bf16(afr[1], b, acc[1][ni], 0, 0, 0);
        }
    }
    float sm[2][4];
#pragma unroll
    for (int mi = 0; mi < 2; mi++)
#pragma unroll
        for (int r = 0; r < 4; r++) sm[mi][r] = 0.f;
#pragma unroll
    for (int mi = 0; mi < 2; mi++)
#pragma unroll
        for (int ni = 0; ni < 4; ni++) {
            int n = wv * 64 + ni * 16 + ln;
            float bb = b1c[n];
#pragma unroll
            for (int r = 0; r < 4; r++) {
                int m = mi * 16 + lg * 4 + r;
                float z = acc[mi][ni][r] * lnd[m] + bb;
                h2[(size_t)(n0 + m) * 256 + n] = z;
                sm[mi][r] += z * z;
            }
        }
#pragma unroll
    for (int mi = 0; mi < 2; mi++)
#pragma unroll
        for (int r = 0; r < 4; r++) {
            float v = sm[mi][r];
            v += __shfl_xor(v, 1);
            v += __shfl_xor(v, 2);
            v += __shfl_xor(v, 4);
            v += __shfl_xor(v, 8);
            if (ln == 0) atomicAdd(&nsq[mi * 16 + lg * 4 + r], v);
        }
    __syncthreads();
    if (t < 32) atomicAdd(&partial[(n0 + t) & 1023], sqrtf(nsq[t]));
}

// ---------------- norm finish ----------------
__global__ void k_normfin(const float* __restrict__ partial, float* factor) {
    __shared__ float red[256];
    int t = threadIdx.x;
    float s = partial[t] + partial[t + 256] + partial[t + 512] + partial[t + 768];
    red[t] = s;
    __syncthreads();
    for (int o = 128; o; o >>= 1) {
        if (t < o) red[t] += red[t + o];
        __syncthreads();
    }
    if (t == 0) factor[0] = 16.0f / (red[0] / (float)N_NODES);
}

// ---------------- pool ----------------
__global__ void k_pool(const float* __restrict__ h2, const float* __restrict__ factor,
                       float* out) {
    int b = blockIdx.x, t = threadIdx.x;
    float fac = factor[0];
    float s = 0.f;
    for (int a = 0; a < ATOMS; a++) s += h2[(size_t)(b * ATOMS + a) * DIM + t];
    s *= fac;
    out[(size_t)b * 512 + t] = s;
    out[(size_t)BATCH * 512 + (size_t)b * DIM + t] = s;
}

// ---------------- target embedding ----------------
__global__ void k_target(const int* __restrict__ id_list, const int* __restrict__ id_list_t,
                         const float* __restrict__ mfea, const float* __restrict__ fea_emb,
                         float* tgt) {
    __shared__ float com[MF];
    int b = blockIdx.x, t = threadIdx.x;
    if (t < MF) {
        int i0 = id_list[b], i1 = id_list[BATCH + b];
        int j0 = id_list_t[b], j1 = id_list_t[BATCH + b];
        com[t] = 0.5f * (mfea[(size_t)i0 * MF + t] + mfea[(size_t)i1 * MF + t])
               + 0.5f * (mfea[(size_t)j0 * MF + t] + mfea[(size_t)j1 * MF + t]);
    }
    __syncthreads();
    float acc = 0.f;
    for (int f = 0; f < MF; f++) acc += com[f] * fea_emb[f * DIM + t];
    tgt[(size_t)b * DIM + t] = acc;
}

// ---------------- attention per (s,b) ----------------
__global__ void k_attn(const int* __restrict__ id_list, const int* __restrict__ neimat,
                       const float* __restrict__ mfea, const float* __restrict__ fea_emb,
                       const float* __restrict__ att_w, const float* __restrict__ att_b,
                       const float* __restrict__ tgt, float* rxn) {
    __shared__ float mitem[MF];
    __shared__ float u[DIM];
    __shared__ float nm[NUM_NEI * MF];
    __shared__ float vv[MF];
    __shared__ float aw[NUM_NEI];
    int sb = blockIdx.x;
    int b = sb & (BATCH - 1);
    int t = threadIdx.x;
    int id = id_list[sb];
    if (t < MF) mitem[t] = mfea[(size_t)id * MF + t];
    for (int i = t; i < NUM_NEI * MF; i += 256) {
        int k = i / MF, f = i - k * MF;
        int nid = neimat[(size_t)id * NUM_NEI + k];
        nm[i] = mfea[(size_t)nid * MF + f];
    }
    __syncthreads();
    float item = 0.f;
    for (int f = 0; f < MF; f++) item += mitem[f] * fea_emb[f * DIM + t];
    float tg = tgt[(size_t)b * DIM + t];
    float awt = att_w[t];
    u[t] = item * tg * awt;
    __syncthreads();
    int wv = t >> 6, lane = t & 63;
    for (int i = 0; i < 5; i++) {
        int f = wv + 8 * i;
        float p = 0.f;
#pragma unroll
        for (int j = 0; j < 4; j++) p += u[lane + 64 * j] * fea_emb[f * DIM + lane + 64 * j];
#pragma unroll
        for (int off = 32; off; off >>= 1) p += __shfl_down(p, off, 64);
        if (lane == 0) vv[f] = p;
    }
    __syncthreads();
    if (wv == 0) {
        float lg = -1e30f;
        if (lane < NUM_NEI) {
            lg = att_b[0];
            for (int f = 0; f < MF; f++) lg += nm[lane * MF + f] * vv[f];
        }
        float m = lg;
#pragma unroll
        for (int off = 16; off; off >>= 1) m = fmaxf(m, __shfl_xor(m, off, 32));
        float e = (lane < NUM_NEI) ? __expf(lg - m) : 0.f;
        float ssum = e;
#pragma unroll
        for (int off = 16; off; off >>= 1) ssum += __shfl_xor(ssum, off, 32);
        if (lane < NUM_NEI) aw[lane] = e / ssum;
    }
    __syncthreads();
    if (t < MF) {
        float w = 0.f;
        for (int k = 0; k < NUM_NEI; k++) w += aw[k] * nm[k * MF + t];
        vv[t] = w;
    }
    __syncthreads();
    float na = 0.f;
    for (int f = 0; f < MF; f++) na += vv[f] * fea_emb[f * DIM + t];
    rxn[(size_t)sb * DIM + t] = item + na;
}

// ---------------- final ----------------
__global__ void k_final(const float* __restrict__ rxn, const float* __restrict__ crosscl_w,
                        const float* __restrict__ crosscl_b, float* out) {
    __shared__ float mre[DIM];
    int b = blockIdx.x, t = threadIdx.x;
    float m = 0.5f * (rxn[(size_t)b * DIM + t] + rxn[(size_t)(BATCH + b) * DIM + t]);
    out[(size_t)b * 512 + DIM + t] = m;
    mre[t] = m;
    __syncthreads();
    float acc = crosscl_b[t];
    for (int uu = 0; uu < DIM; uu++) acc += mre[uu] * crosscl_w[uu * DIM + t];
    out[(size_t)BATCH * 768 + (size_t)b * DIM + t] = acc;
}

extern "C" void kernel_launch(void* const* d_in, const int* in_sizes, int n_in,
                              void* d_out, int out_size, void* d_ws, size_t ws_size,
                              hipStream_t stream) {
    const int*   node_feat = (const int*)d_in[0];
    const int*   edge_src  = (const int*)d_in[1];
    const int*   edge_dst  = (const int*)d_in[2];
    const int*   id_list   = (const int*)d_in[4];
    const int*   id_list_t = (const int*)d_in[5];
    const float* all_mfea  = (const float*)d_in[6];
    const int*   neimat    = (const int*)d_in[7];
    const float* W0        = (const float*)d_in[8];
    const float* b0        = (const float*)d_in[9];
    const float* W1        = (const float*)d_in[10];
    const float* b1        = (const float*)d_in[11];
    const float* fea_emb   = (const float*)d_in[12];
    const float* att_w     = (const float*)d_in[13];
    const float* att_b     = (const float*)d_in[14];
    const float* crosscl_w = (const float*)d_in[15];
    const float* crosscl_b = (const float*)d_in[16];
    float* out = (float*)d_out;

    char* ws = (char*)d_ws;
    int*   deg_out   = (int*)ws;            ws += (size_t)N_NODES * 4;
    int*   deg_in    = (int*)ws;            ws += (size_t)N_NODES * 4;
    float* partial   = (float*)ws;          ws += 1024 * 4;
    float* factor    = (float*)ws;          ws += 256;
    int*   row_start = (int*)ws;            ws += (size_t)N_NODES * 4;
    int*   cursor    = (int*)ws;            ws += (size_t)N_NODES * 4;
    int*   csr_srcb  = (int*)ws;            ws += (size_t)N_EDGES * 4;
    int*   chunk_sums= (int*)ws;            ws += NCHUNK * 4;
    int*   chunk_off = (int*)ws;            ws += NCHUNK * 4;
    unsigned short* w0bt = (unsigned short*)ws; ws += (size_t)256 * 64 * 2;
    unsigned short* w1bt = (unsigned short*)ws; ws += (size_t)256 * 256 * 2;
    unsigned short* h1b  = (unsigned short*)ws; ws += (size_t)N_NODES * DIM * 2;
    float* h2        = (float*)ws;          ws += (size_t)N_NODES * DIM * 4;
    float* tgt       = (float*)ws;          ws += (size_t)BATCH * DIM * 4;
    float* rxn       = (float*)ws;          ws += (size_t)2 * BATCH * DIM * 4;

    hipMemsetAsync(deg_out, 0, (size_t)N_NODES * 8 + 1024 * 4 + 256, stream);

    k_deg<<<(N_EDGES + 255) / 256, 256, 0, stream>>>(edge_src, edge_dst, deg_out, deg_in);
    k_scan_chunk<<<NCHUNK, 256, 0, stream>>>(deg_in, row_start, chunk_sums);
    k_scan_top<<<1, 256, 0, stream>>>(chunk_sums, chunk_off);
    k_add_off<<<N_NODES / 256, 256, 0, stream>>>(row_start, chunk_off, cursor);
    k_csr_fill<<<(N_EDGES + 255) / 256, 256, 0, stream>>>(edge_src, edge_dst, cursor, csr_srcb);
    k_prepw<<<256, 256, 0, stream>>>(W0, W1, w0bt, w1bt);

    k_gcn0<<<N_NODES / 32, 256, 0, stream>>>(node_feat, row_start, csr_srcb, deg_in,
                                             deg_out, w0bt, b0, h1b);
    k_gcn1<<<N_NODES / 32, 256, 0, stream>>>(h1b, row_start, csr_srcb, deg_in,
                                             w1bt, b1, h2, partial);
    k_normfin<<<1, 256, 0, stream>>>(partial, factor);
    k_pool<<<BATCH, 256, 0, stream>>>(h2, factor, out);
    k_target<<<BATCH, 256, 0, stream>>>(id_list, id_list_t, all_mfea, fea_emb, tgt);
    k_attn<<<2 * BATCH, 256, 0, stream>>>(id_list, neimat, all_mfea, fea_emb,
                                          att_w, att_b, tgt, rxn);
    k_final<<<BATCH, 256, 0, stream>>>(rxn, crosscl_w, crosscl_b, out);
}

// Round 5
// 194.324 us; speedup vs baseline: 2.9724x; 1.0675x over previous
//
#include <hip/hip_runtime.h>
#include <math.h>

#define N_NODES 61440
#define N_EDGES 245760
#define BATCH   2048
#define ATOMS   30
#define F_LEN   64
#define DIM     256
#define NUM_NEI 32
#define MF      40
#define ECAP    512

typedef __attribute__((ext_vector_type(8))) short s8v;
typedef __attribute__((ext_vector_type(4))) float f4v;

__device__ __forceinline__ unsigned short f2bf(float x) {
    union { float f; unsigned u; } c; c.f = x;
    unsigned r = (c.u + 0x7FFFu + ((c.u >> 16) & 1u)) >> 16;
    return (unsigned short)r;
}
__device__ __forceinline__ float bf2f(unsigned short u) {
    union { unsigned u; float f; } c; c.u = ((unsigned)u) << 16;
    return c.f;
}

// ---------------- degree counts ----------------
__global__ void k_deg(const int* __restrict__ esrc, const int* __restrict__ edst,
                      int* deg_out, int* deg_in) {
    int e = blockIdx.x * 256 + threadIdx.x;
    if (e < N_EDGES) {
        atomicAdd(&deg_out[esrc[e]], 1);
        atomicAdd(&deg_in[edst[e]], 1);
    }
}

// ---------------- CSR segment allocation: wave prefix + 1 atomic/wave ----------------
// Segments are contiguous within each 64-node wave region, so any aligned 32-node
// tile [n0, n0+32) has contiguous edge storage [row_start[n0], row_start[n0+31]+deg).
__global__ void k_alloc(const int* __restrict__ deg_in, int* row_start, int* cursor,
                        int* counter) {
    int t = threadIdx.x;
    int n = blockIdx.x * 256 + t;
    int lane = t & 63;
    int d = deg_in[n];
    int p = d;
#pragma unroll
    for (int o = 1; o < 64; o <<= 1) { int v = __shfl_up(p, o, 64); if (lane >= o) p += v; }
    int base = 0;
    if (lane == 63) base = atomicAdd(counter, p);
    base = __shfl(base, 63, 64);
    int v = base + p - d;
    row_start[n] = v;
    cursor[n] = v;
}

__global__ void k_csr_fill(const int* __restrict__ esrc, const int* __restrict__ edst,
                           int* cursor, int* csr_src) {
    int e = blockIdx.x * 256 + threadIdx.x;
    if (e < N_EDGES) {
        int p = atomicAdd(&cursor[edst[e]], 1);
        csr_src[p] = esrc[e];
    }
}

// ---------------- weight prep: bf16 transposed copies ----------------
__global__ void k_prepw(const float* __restrict__ W0, const float* __restrict__ W1,
                        unsigned short* w0bt, unsigned short* w1bt) {
    int n = blockIdx.x, k = threadIdx.x;
    w1bt[(size_t)n * 256 + k] = f2bf(W1[(size_t)k * 256 + n]);
    if (k < 64) w0bt[(size_t)n * 64 + k] = f2bf(W0[(size_t)k * 256 + n]);
}

// ---------------- fused layer-0: CSR gather one-hot + MFMA gemm -> h1 bf16 ----------------
__global__ __launch_bounds__(256) void k_gcn0(
    const int* __restrict__ nf, const int* __restrict__ row_start,
    const int* __restrict__ csr_src, const int* __restrict__ deg_in,
    const int* __restrict__ deg_out, const unsigned short* __restrict__ w0bt,
    const float* __restrict__ b0, unsigned short* __restrict__ h1b) {
    __shared__ float la0[32 * 68];
    __shared__ int4  enf[ECAP];
    __shared__ float ens[ECAP];
    __shared__ int   rs[33];
    __shared__ float lnd[32], lns[32];
    __shared__ float b0c[256];
    int n0 = blockIdx.x * 32;
    int t = threadIdx.x;
    if (t < 32) rs[t] = row_start[n0 + t];
    if (t == 0) rs[32] = row_start[n0 + 31] + deg_in[n0 + 31];
    if (t < 32) {
        lnd[t] = rsqrtf((float)max(deg_in[n0 + t], 1));
        lns[t] = rsqrtf((float)max(deg_out[n0 + t], 1));
    }
    b0c[t] = b0[t];
    __syncthreads();
    int beg0 = rs[0];
    int tot = rs[32] - beg0; if (tot > ECAP) tot = ECAP;
    for (int e = t; e < tot; e += 256) {
        int s = csr_src[beg0 + e];
        enf[e] = ((const int4*)nf)[s];
        ens[e] = rsqrtf((float)max(deg_out[s], 1));
    }
    __syncthreads();
    {   // build la0[row][64] one-hot aggregate
        int row = t >> 3, kc = (t & 7) * 8;
        float a[8];
#pragma unroll
        for (int j = 0; j < 8; j++) a[j] = 0.f;
        int lo = rs[row] - beg0, hi = rs[row + 1] - beg0;
        if (hi > tot) hi = tot;
        for (int e = lo; e < hi; e++) {
            int4 f = enf[e]; float w = ens[e];
#pragma unroll
            for (int j = 0; j < 8; j++) {
                int k = kc + j;
                a[j] += w * (float)((f.x == k) + (f.y == k) + (f.z == k) + (f.w == k));
            }
        }
#pragma unroll
        for (int j = 0; j < 8; j++) la0[row * 68 + kc + j] = a[j];
    }
    __syncthreads();
    int lane = t & 63, wv = t >> 6;
    int ln = lane & 15, lg = lane >> 4;
    f4v acc[2][4];
#pragma unroll
    for (int mi = 0; mi < 2; mi++)
#pragma unroll
        for (int ni = 0; ni < 4; ni++) acc[mi][ni] = (f4v)0.f;
#pragma unroll
    for (int kst = 0; kst < 2; kst++) {
        s8v afr[2];
#pragma unroll
        for (int mi = 0; mi < 2; mi++) {
            const float* p = &la0[(mi * 16 + ln) * 68 + kst * 32 + lg * 8];
            f4v lo = *(const f4v*)p;
            f4v hi = *(const f4v*)(p + 4);
            s8v a;
#pragma unroll
            for (int j = 0; j < 4; j++) { a[j] = (short)f2bf(lo[j]); a[4 + j] = (short)f2bf(hi[j]); }
            afr[mi] = a;
        }
#pragma unroll
        for (int ni = 0; ni < 4; ni++) {
            int n = wv * 64 + ni * 16 + ln;
            s8v b = *(const s8v*)&w0bt[(size_t)n * 64 + kst * 32 + lg * 8];
            acc[0][ni] = __builtin_amdgcn_mfma_f32_16x16x32_bf16(afr[0], b, acc[0][ni], 0, 0, 0);
            acc[1][ni] = __builtin_amdgcn_mfma_f32_16x16x32_bf16(afr[1], b, acc[1][ni], 0, 0, 0);
        }
    }
#pragma unroll
    for (int mi = 0; mi < 2; mi++)
#pragma unroll
        for (int ni = 0; ni < 4; ni++) {
            int n = wv * 64 + ni * 16 + ln;
            float bb = b0c[n];
#pragma unroll
            for (int r = 0; r < 4; r++) {
                int m = mi * 16 + lg * 4 + r;
                float z = acc[mi][ni][r] * lnd[m] + bb;
                z = fmaxf(z, 0.f) * lns[m];
                h1b[(size_t)(n0 + m) * 256 + n] = f2bf(z);
            }
        }
}

// ---------------- fused layer-1: CSR gather (4-row MLP) + MFMA + norm -> h2 bf16 ----------------
__global__ __launch_bounds__(256) void k_gcn1(
    const unsigned short* __restrict__ h1b, const int* __restrict__ row_start,
    const int* __restrict__ csr_src, const int* __restrict__ deg_in,
    const unsigned short* __restrict__ w1bt, const float* __restrict__ b1,
    unsigned short* __restrict__ h2b, float* __restrict__ partial) {
    __shared__ unsigned short lab[32 * 264];
    __shared__ int   ecache[ECAP];
    __shared__ int   rs[33];
    __shared__ float lnd[32];
    __shared__ float b1c[256];
    __shared__ float nsq[32];
    int n0 = blockIdx.x * 32;
    int t = threadIdx.x;
    if (t < 32) rs[t] = row_start[n0 + t];
    if (t == 0) rs[32] = row_start[n0 + 31] + deg_in[n0 + 31];
    if (t < 32) {
        lnd[t] = rsqrtf((float)max(deg_in[n0 + t], 1));
        nsq[t] = 0.f;
    }
    b1c[t] = b1[t];
    __syncthreads();
    int beg0 = rs[0];
    int tot = rs[32] - beg0; if (tot > ECAP) tot = ECAP;
    for (int e = t; e < tot; e += 256) ecache[e] = csr_src[beg0 + e];
    __syncthreads();
    // gather: thread owns 8 cols x 4 interleaved rows; 4 independent loads/iter
    {
        int gr = t >> 5;             // row base 0..7
        int gc = (t & 31) * 8;       // column octet
        int lo[4], hi[4];
#pragma unroll
        for (int r = 0; r < 4; r++) {
            int i = gr + r * 8;
            lo[r] = rs[i] - beg0;
            hi[r] = rs[i + 1] - beg0;
            if (hi[r] > tot) hi[r] = tot;
        }
        float a[4][8];
#pragma unroll
        for (int r = 0; r < 4; r++)
#pragma unroll
            for (int j = 0; j < 8; j++) a[r][j] = 0.f;
        int mx = 0;
#pragma unroll
        for (int r = 0; r < 4; r++) mx = max(mx, hi[r] - lo[r]);
        for (int it = 0; it < mx; ++it) {
#pragma unroll
            for (int r = 0; r < 4; r++) {
                int e = lo[r] + it;
                if (e < hi[r]) {
                    int s = ecache[e];
                    s8v v = *(const s8v*)&h1b[(size_t)s * 256 + gc];
#pragma unroll
                    for (int j = 0; j < 8; j++) a[r][j] += bf2f((unsigned short)v[j]);
                }
            }
        }
#pragma unroll
        for (int r = 0; r < 4; r++) {
            int i = gr + r * 8;
            s8v ov;
#pragma unroll
            for (int j = 0; j < 8; j++) ov[j] = (short)f2bf(a[r][j]);
            *(s8v*)&lab[i * 264 + gc] = ov;
        }
    }
    __syncthreads();
    int lane = t & 63, wv = t >> 6;
    int ln = lane & 15, lg = lane >> 4;
    f4v acc[2][4];
#pragma unroll
    for (int mi = 0; mi < 2; mi++)
#pragma unroll
        for (int ni = 0; ni < 4; ni++) acc[mi][ni] = (f4v)0.f;
#pragma unroll 2
    for (int kst = 0; kst < 8; kst++) {
        s8v afr[2];
#pragma unroll
        for (int mi = 0; mi < 2; mi++)
            afr[mi] = *(const s8v*)&lab[(mi * 16 + ln) * 264 + kst * 32 + lg * 8];
#pragma unroll
        for (int ni = 0; ni < 4; ni++) {
            int n = wv * 64 + ni * 16 + ln;
            s8v b = *(const s8v*)&w1bt[(size_t)n * 256 + kst * 32 + lg * 8];
            acc[0][ni] = __builtin_amdgcn_mfma_f32_16x16x32_bf16(afr[0], b, acc[0][ni], 0, 0, 0);
            acc[1][ni] = __builtin_amdgcn_mfma_f32_16x16x32_bf16(afr[1], b, acc[1][ni], 0, 0, 0);
        }
    }
    float sm[2][4];
#pragma unroll
    for (int mi = 0; mi < 2; mi++)
#pragma unroll
        for (int r = 0; r < 4; r++) sm[mi][r] = 0.f;
#pragma unroll
    for (int mi = 0; mi < 2; mi++)
#pragma unroll
        for (int ni = 0; ni < 4; ni++) {
            int n = wv * 64 + ni * 16 + ln;
            float bb = b1c[n];
#pragma unroll
            for (int r = 0; r < 4; r++) {
                int m = mi * 16 + lg * 4 + r;
                float z = acc[mi][ni][r] * lnd[m] + bb;
                h2b[(size_t)(n0 + m) * 256 + n] = f2bf(z);
                sm[mi][r] += z * z;
            }
        }
#pragma unroll
    for (int mi = 0; mi < 2; mi++)
#pragma unroll
        for (int r = 0; r < 4; r++) {
            float v = sm[mi][r];
            v += __shfl_xor(v, 1);
            v += __shfl_xor(v, 2);
            v += __shfl_xor(v, 4);
            v += __shfl_xor(v, 8);
            if (ln == 0) atomicAdd(&nsq[mi * 16 + lg * 4 + r], v);
        }
    __syncthreads();
    if (t < 32) atomicAdd(&partial[(n0 + t) & 1023], sqrtf(nsq[t]));
}

// ---------------- norm finish ----------------
__global__ void k_normfin(const float* __restrict__ partial, float* factor) {
    __shared__ float red[256];
    int t = threadIdx.x;
    float s = partial[t] + partial[t + 256] + partial[t + 512] + partial[t + 768];
    red[t] = s;
    __syncthreads();
    for (int o = 128; o; o >>= 1) {
        if (t < o) red[t] += red[t + o];
        __syncthreads();
    }
    if (t == 0) factor[0] = 16.0f / (red[0] / (float)N_NODES);
}

// ---------------- pool (reads bf16 h2) ----------------
__global__ void k_pool(const unsigned short* __restrict__ h2b,
                       const float* __restrict__ factor, float* out) {
    int b = blockIdx.x, t = threadIdx.x;
    float fac = factor[0];
    float s = 0.f;
    for (int a = 0; a < ATOMS; a++) s += bf2f(h2b[(size_t)(b * ATOMS + a) * DIM + t]);
    s *= fac;
    out[(size_t)b * 512 + t] = s;
    out[(size_t)BATCH * 512 + (size_t)b * DIM + t] = s;
}

// ---------------- fused reaction: target + attention(s=0,1) + mean + crosscl ----------------
__global__ __launch_bounds__(256) void k_rxn(
    const int* __restrict__ id_list, const int* __restrict__ id_list_t,
    const int* __restrict__ neimat, const float* __restrict__ mfea,
    const float* __restrict__ fea_emb, const float* __restrict__ att_w,
    const float* __restrict__ att_b, const float* __restrict__ crosscl_w,
    const float* __restrict__ crosscl_b, float* __restrict__ out) {
    __shared__ float com[MF];
    __shared__ float mitem[MF];
    __shared__ float u[DIM];
    __shared__ float nm[NUM_NEI * MF];
    __shared__ float vv[MF];
    __shared__ float aw[NUM_NEI];
    __shared__ float mre[DIM];
    int b = blockIdx.x;
    int t = threadIdx.x;
    int wv = t >> 6, lane = t & 63;
    if (t < MF) {
        int i0 = id_list[b], i1 = id_list[BATCH + b];
        int j0 = id_list_t[b], j1 = id_list_t[BATCH + b];
        com[t] = 0.5f * (mfea[(size_t)i0 * MF + t] + mfea[(size_t)i1 * MF + t])
               + 0.5f * (mfea[(size_t)j0 * MF + t] + mfea[(size_t)j1 * MF + t]);
    }
    __syncthreads();
    float tg = 0.f;
    for (int f = 0; f < MF; f++) tg += com[f] * fea_emb[f * DIM + t];
    float awt = att_w[t];
    float msum = 0.f;
    for (int s = 0; s < 2; s++) {
        int id = id_list[s * BATCH + b];
        __syncthreads();             // protect nm/vv/aw reuse across s
        if (t < MF) mitem[t] = mfea[(size_t)id * MF + t];
        for (int i = t; i < NUM_NEI * MF; i += 256) {
            int k = i / MF, f = i - k * MF;
            int nid = neimat[(size_t)id * NUM_NEI + k];
            nm[i] = mfea[(size_t)nid * MF + f];
        }
        __syncthreads();
        float item = 0.f;
        for (int f = 0; f < MF; f++) item += mitem[f] * fea_emb[f * DIM + t];
        u[t] = item * tg * awt;
        __syncthreads();
        // v[f] = sum_t u[t]*fea_emb[f,t]  (8 waves x 5 f's each)
        for (int i = 0; i < 5; i++) {
            int f = wv + 8 * i;
            float p = 0.f;
#pragma unroll
            for (int j = 0; j < 4; j++) p += u[lane + 64 * j] * fea_emb[f * DIM + lane + 64 * j];
#pragma unroll
            for (int off = 32; off; off >>= 1) p += __shfl_down(p, off, 64);
            if (lane == 0) vv[f] = p;
        }
        __syncthreads();
        if (wv == 0) {
            float lg = -1e30f;
            if (lane < NUM_NEI) {
                lg = att_b[0];
                for (int f = 0; f < MF; f++) lg += nm[lane * MF + f] * vv[f];
            }
            float m = lg;
#pragma unroll
            for (int off = 16; off; off >>= 1) m = fmaxf(m, __shfl_xor(m, off, 32));
            float e = (lane < NUM_NEI) ? __expf(lg - m) : 0.f;
            float ssum = e;
#pragma unroll
            for (int off = 16; off; off >>= 1) ssum += __shfl_xor(ssum, off, 32);
            if (lane < NUM_NEI) aw[lane] = e / ssum;
        }
        __syncthreads();
        if (t < MF) {
            float w = 0.f;
            for (int k = 0; k < NUM_NEI; k++) w += aw[k] * nm[k * MF + t];
            vv[t] = w;
        }
        __syncthreads();
        float na = 0.f;
        for (int f = 0; f < MF; f++) na += vv[f] * fea_emb[f * DIM + t];
        msum += item + na;
    }
    float m = 0.5f * msum;
    out[(size_t)b * 512 + DIM + t] = m;          // mol_embedding[:, 256:]
    mre[t] = m;
    __syncthreads();
    float acc = crosscl_b[t];
    for (int uu = 0; uu < DIM; uu++) acc += mre[uu] * crosscl_w[uu * DIM + t];
    out[(size_t)BATCH * 768 + (size_t)b * DIM + t] = acc;   // mol_x_embedding
}

extern "C" void kernel_launch(void* const* d_in, const int* in_sizes, int n_in,
                              void* d_out, int out_size, void* d_ws, size_t ws_size,
                              hipStream_t stream) {
    const int*   node_feat = (const int*)d_in[0];
    const int*   edge_src  = (const int*)d_in[1];
    const int*   edge_dst  = (const int*)d_in[2];
    const int*   id_list   = (const int*)d_in[4];
    const int*   id_list_t = (const int*)d_in[5];
    const float* all_mfea  = (const float*)d_in[6];
    const int*   neimat    = (const int*)d_in[7];
    const float* W0        = (const float*)d_in[8];
    const float* b0        = (const float*)d_in[9];
    const float* W1        = (const float*)d_in[10];
    const float* b1        = (const float*)d_in[11];
    const float* fea_emb   = (const float*)d_in[12];
    const float* att_w     = (const float*)d_in[13];
    const float* att_b     = (const float*)d_in[14];
    const float* crosscl_w = (const float*)d_in[15];
    const float* crosscl_b = (const float*)d_in[16];
    float* out = (float*)d_out;

    char* ws = (char*)d_ws;
    int*   deg_out   = (int*)ws;            ws += (size_t)N_NODES * 4;
    int*   deg_in    = (int*)ws;            ws += (size_t)N_NODES * 4;
    float* partial   = (float*)ws;          ws += 1024 * 4;
    float* factor    = (float*)ws;
    int*   counter   = (int*)(ws + 8);      ws += 256;
    int*   row_start = (int*)ws;            ws += (size_t)N_NODES * 4;
    int*   cursor    = (int*)ws;            ws += (size_t)N_NODES * 4;
    int*   csr_srcb  = (int*)ws;            ws += (size_t)N_EDGES * 4;
    unsigned short* w0bt = (unsigned short*)ws; ws += (size_t)256 * 64 * 2;
    unsigned short* w1bt = (unsigned short*)ws; ws += (size_t)256 * 256 * 2;
    unsigned short* h1b  = (unsigned short*)ws; ws += (size_t)N_NODES * DIM * 2;
    unsigned short* h2b  = (unsigned short*)ws; ws += (size_t)N_NODES * DIM * 2;

    // zero degrees + partial + factor/counter region
    hipMemsetAsync(deg_out, 0, (size_t)N_NODES * 8 + 1024 * 4 + 256, stream);

    k_deg<<<(N_EDGES + 255) / 256, 256, 0, stream>>>(edge_src, edge_dst, deg_out, deg_in);
    k_alloc<<<N_NODES / 256, 256, 0, stream>>>(deg_in, row_start, cursor, counter);
    k_csr_fill<<<(N_EDGES + 255) / 256, 256, 0, stream>>>(edge_src, edge_dst, cursor, csr_srcb);
    k_prepw<<<256, 256, 0, stream>>>(W0, W1, w0bt, w1bt);

    k_gcn0<<<N_NODES / 32, 256, 0, stream>>>(node_feat, row_start, csr_srcb, deg_in,
                                             deg_out, w0bt, b0, h1b);
    k_gcn1<<<N_NODES / 32, 256, 0, stream>>>(h1b, row_start, csr_srcb, deg_in,
                                             w1bt, b1, h2b, partial);
    k_normfin<<<1, 256, 0, stream>>>(partial, factor);
    k_pool<<<BATCH, 256, 0, stream>>>(h2b, factor, out);
    k_rxn<<<BATCH, 256, 0, stream>>>(id_list, id_list_t, neimat, all_mfea, fea_emb,
                                     att_w, att_b, crosscl_w, crosscl_b, out);
}